// Round 5
// baseline (319.472 us; speedup 1.0000x reference)
//
#include <hip/hip_runtime.h>

#define SEQ   2048
#define BATCH 2
#define DIN   768
#define NH    12
#define DH    64
#define QKVN  (NH*3*DH)   /* 2304 */
// Q pre-scale: attention scale folded with log2(e) -> softmax in exp2 domain.
#define QSCALE 0.18033688011112042f  /* 0.125 * log2(e) */

typedef __attribute__((ext_vector_type(8))) short short8;   // 8 bf16 = 4 VGPR
typedef __attribute__((ext_vector_type(4))) float float4v;  // MFMA acc

__device__ __forceinline__ ushort f2bf(float f) {
  union { float f; uint u; } v; v.f = f;
  return (ushort)((v.u + 0x7fffu + ((v.u >> 16) & 1u)) >> 16);  // RNE
}

// ---------------------------------------------------------------------------
// fp32 -> bf16 straight copy (x). one float4 per thread, exact grid.
// ---------------------------------------------------------------------------
__global__ __launch_bounds__(256) void cvt_x(const float* __restrict__ X,
                                             ushort* __restrict__ Xb) {
  int i = blockIdx.x * 256 + threadIdx.x;
  float4 v = ((const float4*)X)[i];
  ushort4 o;
  o.x = f2bf(v.x); o.y = f2bf(v.y); o.z = f2bf(v.z); o.w = f2bf(v.w);
  ((ushort4*)Xb)[i] = o;
}

// ---------------------------------------------------------------------------
// fp32 [K,N] -> bf16 transposed [N,K]. 32x32 LDS tile, 256 threads.
// ---------------------------------------------------------------------------
__global__ __launch_bounds__(256) void cvt_T(const float* __restrict__ W,
                                             ushort* __restrict__ WT,
                                             int Kdim, int Ndim) {
  __shared__ float tile[32][33];
  const int tx = threadIdx.x & 31, tg = threadIdx.x >> 5;
  const int r0 = blockIdx.x * 32, c0 = blockIdx.y * 32;
#pragma unroll
  for (int i = 0; i < 4; ++i) {
    int r = tg + i * 8;
    tile[r][tx] = W[(size_t)(r0 + r) * Ndim + c0 + tx];
  }
  __syncthreads();
#pragma unroll
  for (int i = 0; i < 4; ++i) {
    int c = tg + i * 8;
    WT[(size_t)(c0 + c) * Kdim + r0 + tx] = f2bf(tile[tx][c]);
  }
}

// ---------------------------------------------------------------------------
// Shared MFMA GEMM core: C[128x128] = A[128xK] * BT[128xK]^T, K=768, BK=64.
// 4 waves (2x2), each 64x64 via 4x4 frags of 16x16x32.
// LDS in fragment order [sub(8)][ks(2)][lane(64)][8 bf16] -> all ds ops linear
// per lane (conflict-free), staging covers each (row,kchunk) exactly once.
// ---------------------------------------------------------------------------
#define GEMM_CORE(Abf, BT)                                                     \
  __shared__ ushort As[8192];                                                  \
  __shared__ ushort Bs[8192];                                                  \
  const int t = threadIdx.x;                                                   \
  const int lane = t & 63, wid = t >> 6;                                       \
  const int wr = wid >> 1, wc = wid & 1;                                       \
  const int m0 = blockIdx.x * 128, n0 = blockIdx.y * 128;                      \
  float4v acc[4][4] = {};                                                      \
  for (int k0 = 0; k0 < DIN; k0 += 64) {                                       \
    __syncthreads();                                                           \
    _Pragma("unroll")                                                          \
    for (int i = 0; i < 4; ++i) {                                              \
      int s   = t + i * 256;                                                   \
      int sub = s >> 7, ks = (s >> 6) & 1, l = s & 63;                         \
      int row = sub * 16 + (l & 15);                                           \
      int kc  = ks * 32 + (l >> 4) * 8;                                        \
      *(uint4*)&As[s * 8] =                                                    \
          *(const uint4*)&Abf[(size_t)(m0 + row) * DIN + k0 + kc];             \
      *(uint4*)&Bs[s * 8] =                                                    \
          *(const uint4*)&BT[(size_t)(n0 + row) * DIN + k0 + kc];              \
    }                                                                          \
    __syncthreads();                                                           \
    _Pragma("unroll")                                                          \
    for (int ks = 0; ks < 2; ++ks) {                                           \
      short8 a[4], b[4];                                                       \
      _Pragma("unroll")                                                        \
      for (int mi = 0; mi < 4; ++mi)                                           \
        a[mi] = *(const short8*)&As[(((wr * 4 + mi) * 2 + ks) * 64 + lane) * 8];\
      _Pragma("unroll")                                                        \
      for (int ni = 0; ni < 4; ++ni)                                           \
        b[ni] = *(const short8*)&Bs[(((wc * 4 + ni) * 2 + ks) * 64 + lane) * 8];\
      _Pragma("unroll")                                                        \
      for (int mi = 0; mi < 4; ++mi)                                           \
        _Pragma("unroll")                                                      \
        for (int ni = 0; ni < 4; ++ni)                                         \
          acc[mi][ni] = __builtin_amdgcn_mfma_f32_16x16x32_bf16(               \
              a[mi], b[ni], acc[mi][ni], 0, 0, 0);                             \
    }                                                                          \
  }

// QKV projection: epilogue scatters Q(*QSCALE),K as [BH,N,64], V as [BH,64,N].
__global__ __launch_bounds__(256) void gemm_qkv(const ushort* __restrict__ Abf,
                                                const ushort* __restrict__ BT,
                                                ushort* __restrict__ Q,
                                                ushort* __restrict__ K,
                                                ushort* __restrict__ Vt) {
  GEMM_CORE(Abf, BT)
  const int mbase = m0 + wr * 64;
#pragma unroll
  for (int ni = 0; ni < 4; ++ni) {
    // col = cbase + (lane&15); cbase 16-aligned, rem%64 in {0,16,32,48}
    // so h / which / d-block are fragment-uniform (no crossing).
    const int cbase = n0 + wc * 64 + ni * 16;
    const int h = cbase / 192, rem = cbase % 192;
    const int which = rem / 64;
    const int d0 = (rem % 64) + (lane & 15);
#pragma unroll
    for (int mi = 0; mi < 4; ++mi) {
      const int mrow = mbase + mi * 16 + (lane >> 4) * 4;
      const int bb = mrow >> 11, n = mrow & (SEQ - 1);
      const int bh = bb * NH + h;
      if (which == 2) {
        ushort4 pk;  // acc regs r=0..3 are rows n..n+3 at fixed d -> n-contig
        pk.x = f2bf(acc[mi][ni][0]); pk.y = f2bf(acc[mi][ni][1]);
        pk.z = f2bf(acc[mi][ni][2]); pk.w = f2bf(acc[mi][ni][3]);
        *(ushort4*)&Vt[((size_t)bh * DH + d0) * SEQ + n] = pk;
      } else {
        ushort* dst = (which == 0) ? Q : K;
        const float sc = (which == 0) ? QSCALE : 1.0f;
#pragma unroll
        for (int r = 0; r < 4; ++r)
          dst[((size_t)bh * SEQ + n + r) * DH + d0] = f2bf(acc[mi][ni][r] * sc);
      }
    }
  }
}

// Output projection: fp32 out + bias.
__global__ __launch_bounds__(256) void gemm_out(const ushort* __restrict__ Abf,
                                                const ushort* __restrict__ BT,
                                                const float* __restrict__ bias,
                                                float* __restrict__ Out) {
  GEMM_CORE(Abf, BT)
#pragma unroll
  for (int ni = 0; ni < 4; ++ni) {
    const int c = n0 + wc * 64 + ni * 16 + (lane & 15);
    const float bv = bias[c];
#pragma unroll
    for (int mi = 0; mi < 4; ++mi) {
      const int mrow = m0 + wr * 64 + mi * 16 + (lane >> 4) * 4;
#pragma unroll
      for (int r = 0; r < 4; ++r)
        Out[(size_t)(mrow + r) * DIN + c] = acc[mi][ni][r] + bv;
    }
  }
}

// ---------------------------------------------------------------------------
// Flash attention, bf16 MFMA. grid=(N/64, B*H), 256 thr = 4 independent waves.
// Wave owns 16 q-rows; K/V frags straight from global (L1/L2-resident). P tile
// through per-wave XOR-swizzled LDS. Softmax in exp2 domain (scale pre-folded).
// V-frags hoisted before softmax (global latency hides under VALU chain —
// the lgkmcnt asm's memory clobber would otherwise block the hoist).
//
// P swizzle: byte ^= ((qrow>>2)&3)<<5.  Write banks ((ns^hi)<<3)|(lo>>1):
// 32 banks, 2 lanes/bank on the SAME dword (adjacent bytes). Read: 8
// dword-accesses/bank (b128 wave minimum). Conflict-free both sides.
// ---------------------------------------------------------------------------
__device__ __forceinline__ int p_swz(int qrow, int byte) {
  return byte ^ (((qrow >> 2) & 3) << 5);
}

__global__ __launch_bounds__(256) void attn(const ushort* __restrict__ Q,
                                            const ushort* __restrict__ K,
                                            const ushort* __restrict__ Vt,
                                            ushort* __restrict__ CTX) {
  __shared__ ushort ps[4][1024];  // per-wave 16x64 bf16, XOR-swizzled
  const int t = threadIdx.x, lane = t & 63, wid = t >> 6;
  const int bh = blockIdx.y;
  const int q0 = blockIdx.x * 64 + wid * 16;
  const size_t base = (size_t)bh * SEQ * DH;
  ushort* myps = ps[wid];

  short8 qf[2];  // A-frag: row=lane&15, k=ks*32+(lane>>4)*8 (Q pre-scaled)
#pragma unroll
  for (int ks = 0; ks < 2; ++ks)
    qf[ks] = *(const short8*)&Q[base + (size_t)(q0 + (lane & 15)) * DH +
                                ks * 32 + (lane >> 4) * 8];

  float4v O[4] = {};
  float mrun[4], lrun[4];
#pragma unroll
  for (int r = 0; r < 4; ++r) { mrun[r] = -1e30f; lrun[r] = 0.f; }

  for (int kt = 0; kt < SEQ / 64; ++kt) {
    const int key0 = kt * 64;
    // ---- S = Q K^T : D layout col=key(lane&15), row=qrow((lane>>4)*4+r) ----
    float4v s[4];
#pragma unroll
    for (int ns = 0; ns < 4; ++ns) {
      s[ns] = (float4v){0.f, 0.f, 0.f, 0.f};
#pragma unroll
      for (int ks = 0; ks < 2; ++ks) {
        short8 kf = *(const short8*)&K[base +
            (size_t)(key0 + ns * 16 + (lane & 15)) * DH + ks * 32 + (lane >> 4) * 8];
        s[ns] = __builtin_amdgcn_mfma_f32_16x16x32_bf16(qf[ks], kf, s[ns], 0, 0, 0);
      }
    }
    // ---- hoisted V B-frags (independent of softmax; latency hides below) ----
    short8 vf[4][2];
#pragma unroll
    for (int ns = 0; ns < 4; ++ns)
#pragma unroll
      for (int ks = 0; ks < 2; ++ks)
        vf[ns][ks] = *(const short8*)&Vt[((size_t)bh * DH + ns * 16 + (lane & 15)) * SEQ +
                                         key0 + ks * 32 + (lane >> 4) * 8];
    // ---- online softmax in exp2 domain (16-lane xor reduce per row) ----
    float pv[4][4];
#pragma unroll
    for (int r = 0; r < 4; ++r) {
      float mx = fmaxf(fmaxf(s[0][r], s[1][r]), fmaxf(s[2][r], s[3][r]));
#pragma unroll
      for (int o = 1; o < 16; o <<= 1) mx = fmaxf(mx, __shfl_xor(mx, o));
      float mnew  = fmaxf(mrun[r], mx);
      float alpha = exp2f(mrun[r] - mnew);
      mrun[r] = mnew;
      float rs = 0.f;
#pragma unroll
      for (int ns = 0; ns < 4; ++ns) {
        float p = exp2f(s[ns][r] - mnew);
        pv[ns][r] = p; rs += p;
      }
#pragma unroll
      for (int o = 1; o < 16; o <<= 1) rs += __shfl_xor(rs, o);
      lrun[r] = lrun[r] * alpha + rs;
#pragma unroll
      for (int n2 = 0; n2 < 4; ++n2) O[n2][r] *= alpha;
    }
    // ---- P -> LDS bf16 (swizzled) ----
#pragma unroll
    for (int ns = 0; ns < 4; ++ns)
#pragma unroll
      for (int r = 0; r < 4; ++r) {
        int qrow = (lane >> 4) * 4 + r;
        int key  = ns * 16 + (lane & 15);
        *(ushort*)((char*)myps + p_swz(qrow, qrow * 128 + key * 2)) =
            f2bf(pv[ns][r]);
      }
    // Cross-lane LDS write->read within the wave: drain explicitly. Consumer
    // is a ds_read (memory op), so the "memory" clobber fully orders it.
    asm volatile("s_waitcnt lgkmcnt(0)" ::: "memory");
    // ---- P A-frags: row=qrow(lane&15), k=key contiguous-8 (16B reads) ----
    short8 pf[2];
#pragma unroll
    for (int ks = 0; ks < 2; ++ks) {
      int qrow = lane & 15;
      pf[ks] = *(const short8*)((char*)myps +
          p_swz(qrow, qrow * 128 + ks * 64 + (lane >> 4) * 16));
    }
    // ---- O += P V (pure-register MFMA cluster; setprio per m191 regime) ----
    __builtin_amdgcn_s_setprio(1);
#pragma unroll
    for (int ns = 0; ns < 4; ++ns)
#pragma unroll
      for (int ks = 0; ks < 2; ++ks)
        O[ns] = __builtin_amdgcn_mfma_f32_16x16x32_bf16(pf[ks], vf[ns][ks],
                                                        O[ns], 0, 0, 0);
    __builtin_amdgcn_s_setprio(0);
  }
  // ---- epilogue: normalize, write CTX [B,N,768] bf16 (head-merge fused) ----
  const int bb = bh / NH, h = bh % NH;
#pragma unroll
  for (int r = 0; r < 4; ++r) {
    float inv = 1.0f / lrun[r];
    int n = q0 + (lane >> 4) * 4 + r;
#pragma unroll
    for (int ns = 0; ns < 4; ++ns)
      CTX[((size_t)(bb * SEQ + n)) * DIN + h * DH + ns * 16 + (lane & 15)] =
          f2bf(O[ns][r] * inv);
  }
}

// ---------------------------------------------------------------------------
extern "C" void kernel_launch(void* const* d_in, const int* in_sizes, int n_in,
                              void* d_out, int out_size, void* d_ws, size_t ws_size,
                              hipStream_t stream) {
  const float* x     = (const float*)d_in[0];
  const float* w_qkv = (const float*)d_in[1];
  const float* w_out = (const float*)d_in[2];
  const float* b_out = (const float*)d_in[3];
  float* out = (float*)d_out;

  ushort* ws = (ushort*)d_ws;
  const size_t nX   = (size_t)BATCH * SEQ * DIN;     // 3,145,728
  const size_t nWq  = (size_t)DIN * QKVN;            // 1,769,472
  const size_t nWo  = (size_t)DIN * DIN;             //   589,824
  const size_t nQKV = (size_t)BATCH * NH * SEQ * DH; // 3,145,728

  ushort* xb   = ws;
  ushort* wqT  = xb + nX;
  ushort* woT  = wqT + nWq;
  ushort* Qb   = woT + nWo;
  ushort* Kb   = Qb + nQKV;
  ushort* Vt   = Kb + nQKV;
  ushort* CTX  = Vt + nQKV;   // total ~36.2 MB

  cvt_x<<<dim3(nX / 4 / 256), 256, 0, stream>>>(x, xb);
  cvt_T<<<dim3(DIN / 32, QKVN / 32), 256, 0, stream>>>(w_qkv, wqT, DIN, QKVN);
  cvt_T<<<dim3(DIN / 32, DIN / 32), 256, 0, stream>>>(w_out, woT, DIN, DIN);

  gemm_qkv<<<dim3(BATCH * SEQ / 128, QKVN / 128), 256, 0, stream>>>(
      xb, wqT, Qb, Kb, Vt);
  attn<<<dim3(SEQ / 64, BATCH * NH), 256, 0, stream>>>(Qb, Kb, Vt, CTX);
  gemm_out<<<dim3(BATCH * SEQ / 128, DIN / 128), 256, 0, stream>>>(
      CTX, woT, b_out, out);
}

// Round 6
// 245.510 us; speedup vs baseline: 1.3013x; 1.3013x over previous
//
#include <hip/hip_runtime.h>

#define SEQ   2048
#define BATCH 2
#define DIN   768
#define NH    12
#define DH    64
#define QKVN  (NH*3*DH)   /* 2304 */
// Q pre-scale: attention scale folded with log2(e) -> softmax in exp2 domain.
#define QSCALE 0.18033688011112042f  /* 0.125 * log2(e) */

typedef __attribute__((ext_vector_type(8))) short short8;   // 8 bf16 = 4 VGPR
typedef __attribute__((ext_vector_type(4))) float float4v;  // MFMA acc

__device__ __forceinline__ ushort f2bf(float f) {
  union { float f; uint u; } v; v.f = f;
  return (ushort)((v.u + 0x7fffu + ((v.u >> 16) & 1u)) >> 16);  // RNE
}

// ---------------------------------------------------------------------------
// fp32 -> bf16 straight copy (x). one float4 per thread, exact grid.
// ---------------------------------------------------------------------------
__global__ __launch_bounds__(256) void cvt_x(const float* __restrict__ X,
                                             ushort* __restrict__ Xb) {
  int i = blockIdx.x * 256 + threadIdx.x;
  float4 v = ((const float4*)X)[i];
  ushort4 o;
  o.x = f2bf(v.x); o.y = f2bf(v.y); o.z = f2bf(v.z); o.w = f2bf(v.w);
  ((ushort4*)Xb)[i] = o;
}

// ---------------------------------------------------------------------------
// fp32 [K,N] -> bf16 transposed [N,K]. 32x32 LDS tile, 256 threads.
// ---------------------------------------------------------------------------
__global__ __launch_bounds__(256) void cvt_T(const float* __restrict__ W,
                                             ushort* __restrict__ WT,
                                             int Kdim, int Ndim) {
  __shared__ float tile[32][33];
  const int tx = threadIdx.x & 31, tg = threadIdx.x >> 5;
  const int r0 = blockIdx.x * 32, c0 = blockIdx.y * 32;
#pragma unroll
  for (int i = 0; i < 4; ++i) {
    int r = tg + i * 8;
    tile[r][tx] = W[(size_t)(r0 + r) * Ndim + c0 + tx];
  }
  __syncthreads();
#pragma unroll
  for (int i = 0; i < 4; ++i) {
    int c = tg + i * 8;
    WT[(size_t)(c0 + c) * Kdim + r0 + tx] = f2bf(tile[tx][c]);
  }
}

// ---------------------------------------------------------------------------
// Shared MFMA GEMM core: C[128x128] = A[128xK] * BT[128xK]^T, K=768, BK=64.
// 4 waves (2x2), each 64x64 via 4x4 frags of 16x16x32.
// LDS in fragment order [sub(8)][ks(2)][lane(64)][8 bf16] -> all ds ops linear
// per lane (conflict-free), staging covers each (row,kchunk) exactly once.
// ---------------------------------------------------------------------------
#define GEMM_CORE(Abf, BT)                                                     \
  __shared__ ushort As[8192];                                                  \
  __shared__ ushort Bs[8192];                                                  \
  const int t = threadIdx.x;                                                   \
  const int lane = t & 63, wid = t >> 6;                                       \
  const int wr = wid >> 1, wc = wid & 1;                                       \
  const int m0 = blockIdx.x * 128, n0 = blockIdx.y * 128;                      \
  float4v acc[4][4] = {};                                                      \
  for (int k0 = 0; k0 < DIN; k0 += 64) {                                       \
    __syncthreads();                                                           \
    _Pragma("unroll")                                                          \
    for (int i = 0; i < 4; ++i) {                                              \
      int s   = t + i * 256;                                                   \
      int sub = s >> 7, ks = (s >> 6) & 1, l = s & 63;                         \
      int row = sub * 16 + (l & 15);                                           \
      int kc  = ks * 32 + (l >> 4) * 8;                                        \
      *(uint4*)&As[s * 8] =                                                    \
          *(const uint4*)&Abf[(size_t)(m0 + row) * DIN + k0 + kc];             \
      *(uint4*)&Bs[s * 8] =                                                    \
          *(const uint4*)&BT[(size_t)(n0 + row) * DIN + k0 + kc];              \
    }                                                                          \
    __syncthreads();                                                           \
    _Pragma("unroll")                                                          \
    for (int ks = 0; ks < 2; ++ks) {                                           \
      short8 a[4], b[4];                                                       \
      _Pragma("unroll")                                                        \
      for (int mi = 0; mi < 4; ++mi)                                           \
        a[mi] = *(const short8*)&As[(((wr * 4 + mi) * 2 + ks) * 64 + lane) * 8];\
      _Pragma("unroll")                                                        \
      for (int ni = 0; ni < 4; ++ni)                                           \
        b[ni] = *(const short8*)&Bs[(((wc * 4 + ni) * 2 + ks) * 64 + lane) * 8];\
      _Pragma("unroll")                                                        \
      for (int mi = 0; mi < 4; ++mi)                                           \
        _Pragma("unroll")                                                      \
        for (int ni = 0; ni < 4; ++ni)                                         \
          acc[mi][ni] = __builtin_amdgcn_mfma_f32_16x16x32_bf16(               \
              a[mi], b[ni], acc[mi][ni], 0, 0, 0);                             \
    }                                                                          \
  }

// QKV projection: epilogue scatters Q(*QSCALE),K as [BH,N,64], V as [BH,64,N].
__global__ __launch_bounds__(256) void gemm_qkv(const ushort* __restrict__ Abf,
                                                const ushort* __restrict__ BT,
                                                ushort* __restrict__ Q,
                                                ushort* __restrict__ K,
                                                ushort* __restrict__ Vt) {
  GEMM_CORE(Abf, BT)
  const int mbase = m0 + wr * 64;
#pragma unroll
  for (int ni = 0; ni < 4; ++ni) {
    // col = cbase + (lane&15); cbase 16-aligned, rem%64 in {0,16,32,48}
    // so h / which / d-block are fragment-uniform (no crossing).
    const int cbase = n0 + wc * 64 + ni * 16;
    const int h = cbase / 192, rem = cbase % 192;
    const int which = rem / 64;
    const int d0 = (rem % 64) + (lane & 15);
#pragma unroll
    for (int mi = 0; mi < 4; ++mi) {
      const int mrow = mbase + mi * 16 + (lane >> 4) * 4;
      const int bb = mrow >> 11, n = mrow & (SEQ - 1);
      const int bh = bb * NH + h;
      if (which == 2) {
        ushort4 pk;  // acc regs r=0..3 are rows n..n+3 at fixed d -> n-contig
        pk.x = f2bf(acc[mi][ni][0]); pk.y = f2bf(acc[mi][ni][1]);
        pk.z = f2bf(acc[mi][ni][2]); pk.w = f2bf(acc[mi][ni][3]);
        *(ushort4*)&Vt[((size_t)bh * DH + d0) * SEQ + n] = pk;
      } else {
        ushort* dst = (which == 0) ? Q : K;
        const float sc = (which == 0) ? QSCALE : 1.0f;
#pragma unroll
        for (int r = 0; r < 4; ++r)
          dst[((size_t)bh * SEQ + n + r) * DH + d0] = f2bf(acc[mi][ni][r] * sc);
      }
    }
  }
}

// Output projection: fp32 out + bias.
__global__ __launch_bounds__(256) void gemm_out(const ushort* __restrict__ Abf,
                                                const ushort* __restrict__ BT,
                                                const float* __restrict__ bias,
                                                float* __restrict__ Out) {
  GEMM_CORE(Abf, BT)
#pragma unroll
  for (int ni = 0; ni < 4; ++ni) {
    const int c = n0 + wc * 64 + ni * 16 + (lane & 15);
    const float bv = bias[c];
#pragma unroll
    for (int mi = 0; mi < 4; ++mi) {
      const int mrow = m0 + wr * 64 + mi * 16 + (lane >> 4) * 4;
#pragma unroll
      for (int r = 0; r < 4; ++r)
        Out[(size_t)(mrow + r) * DIN + c] = acc[mi][ni][r] + bv;
    }
  }
}

// ---------------------------------------------------------------------------
// Flash attention, bf16 MFMA. grid=(N/64, B*H), 256 thr = 4 waves.
// R5 profile said latency-bound (MfmaUtil 5.5%, VALU 32%, occupancy 29%):
// every wave re-loaded identical K/V frags from global on the critical path.
// Now: block-cooperative K/V staging into double-buffered LDS, issue-early/
// write-late (loads for kt+1 in flight across tile kt's compute), ONE barrier
// per iteration (compute reads buf[cur], staging writes buf[cur^1]; the
// barrier at iter end makes writes visible and fences next iter's writes
// against this iter's reads).
//
// K/V tile swizzle: byte ^= ((row&7)<<4), identical on write and read side.
// Both sides hit the b128 wave-minimum 8 dword-accesses/bank (desk-verified).
// P swizzle p_swz unchanged (conflict-free both sides).
// ---------------------------------------------------------------------------
__device__ __forceinline__ int p_swz(int qrow, int byte) {
  return byte ^ (((qrow >> 2) & 3) << 5);
}

__global__ __launch_bounds__(256) void attn(const ushort* __restrict__ Q,
                                            const ushort* __restrict__ K,
                                            const ushort* __restrict__ Vt,
                                            ushort* __restrict__ CTX) {
  __shared__ ushort Ks[2][4096];  // [buf][key(64) x dim(64)] swizzled, 8 KB ea
  __shared__ ushort Vs[2][4096];  // [buf][dim(64) x key(64)] swizzled
  __shared__ ushort ps[4][1024];  // per-wave 16x64 bf16, XOR-swizzled
  const int t = threadIdx.x, lane = t & 63, wid = t >> 6;
  const int bh = blockIdx.y;
  const int q0 = blockIdx.x * 64 + wid * 16;
  const size_t base = (size_t)bh * SEQ * DH;
  const ushort* Kg = K + base;                      // [N][64] row-major
  const ushort* Vg = Vt + (size_t)bh * DH * SEQ;    // [64][N] d-major
  ushort* myps = ps[wid];

  short8 qf[2];  // A-frag: row=lane&15, k=ks*32+(lane>>4)*8 (Q pre-scaled)
#pragma unroll
  for (int ks = 0; ks < 2; ++ks)
    qf[ks] = *(const short8*)&Q[base + (size_t)(q0 + (lane & 15)) * DH +
                                ks * 32 + (lane >> 4) * 8];

  float4v O[4] = {};
  float mrun[4], lrun[4];
#pragma unroll
  for (int r = 0; r < 4; ++r) { mrun[r] = -1e30f; lrun[r] = 0.f; }

  // ---- prologue: stage tile 0 into buf 0 ----
  uint4 kreg[2], vreg[2];
#pragma unroll
  for (int i = 0; i < 2; ++i) {
    int c = t + i * 256;                       // 16B chunk id, 0..511
    kreg[i] = *(const uint4*)&Kg[c * 8];       // K tile contiguous 8 KB
    vreg[i] = *(const uint4*)&Vg[(size_t)(c >> 3) * SEQ + (c & 7) * 8];
  }
#pragma unroll
  for (int i = 0; i < 2; ++i) {
    int c = t + i * 256;
    int sw = (c * 16) ^ (((c >> 3) & 7) << 4);
    *(uint4*)((char*)&Ks[0][0] + sw) = kreg[i];
    *(uint4*)((char*)&Vs[0][0] + sw) = vreg[i];
  }
  __syncthreads();

  const int NT = SEQ / 64;
  for (int kt = 0; kt < NT; ++kt) {
    const int cur = kt & 1;
    const char* Kl = (const char*)&Ks[cur][0];
    const char* Vl = (const char*)&Vs[cur][0];
    // ---- issue next tile's global loads (consumed at bottom) ----
    if (kt + 1 < NT) {
      const int key0n = (kt + 1) * 64;
#pragma unroll
      for (int i = 0; i < 2; ++i) {
        int c = t + i * 256;
        kreg[i] = *(const uint4*)&Kg[(size_t)key0n * DH + c * 8];
        vreg[i] = *(const uint4*)&Vg[(size_t)(c >> 3) * SEQ + key0n + (c & 7) * 8];
      }
    }
    // ---- S = Q K^T : D layout col=key(lane&15), row=qrow((lane>>4)*4+r) ----
    float4v s[4];
#pragma unroll
    for (int ns = 0; ns < 4; ++ns) {
      s[ns] = (float4v){0.f, 0.f, 0.f, 0.f};
#pragma unroll
      for (int ks = 0; ks < 2; ++ks) {
        int row = ns * 16 + (lane & 15);   // key within tile
        int byte = (row * 128 + ks * 64 + (lane >> 4) * 16) ^ ((row & 7) << 4);
        short8 kf = *(const short8*)(Kl + byte);
        s[ns] = __builtin_amdgcn_mfma_f32_16x16x32_bf16(qf[ks], kf, s[ns], 0, 0, 0);
      }
    }
    // ---- online softmax in exp2 domain (16-lane xor reduce per row) ----
    float pv[4][4];
#pragma unroll
    for (int r = 0; r < 4; ++r) {
      float mx = fmaxf(fmaxf(s[0][r], s[1][r]), fmaxf(s[2][r], s[3][r]));
#pragma unroll
      for (int o = 1; o < 16; o <<= 1) mx = fmaxf(mx, __shfl_xor(mx, o));
      float mnew  = fmaxf(mrun[r], mx);
      float alpha = exp2f(mrun[r] - mnew);
      mrun[r] = mnew;
      float rs = 0.f;
#pragma unroll
      for (int ns = 0; ns < 4; ++ns) {
        float p = exp2f(s[ns][r] - mnew);
        pv[ns][r] = p; rs += p;
      }
#pragma unroll
      for (int o = 1; o < 16; o <<= 1) rs += __shfl_xor(rs, o);
      lrun[r] = lrun[r] * alpha + rs;
#pragma unroll
      for (int n2 = 0; n2 < 4; ++n2) O[n2][r] *= alpha;
    }
    // ---- P -> LDS bf16 (swizzled) ----
#pragma unroll
    for (int ns = 0; ns < 4; ++ns)
#pragma unroll
      for (int r = 0; r < 4; ++r) {
        int qrow = (lane >> 4) * 4 + r;
        int key  = ns * 16 + (lane & 15);
        *(ushort*)((char*)myps + p_swz(qrow, qrow * 128 + key * 2)) =
            f2bf(pv[ns][r]);
      }
    // Cross-lane LDS write->read within the wave: drain explicitly. Consumer
    // is a ds_read (memory op), so the "memory" clobber fully orders it.
    asm volatile("s_waitcnt lgkmcnt(0)" ::: "memory");
    // ---- P A-frags: row=qrow(lane&15), k=key contiguous-8 (16B reads) ----
    short8 pf[2];
#pragma unroll
    for (int ks = 0; ks < 2; ++ks) {
      int qrow = lane & 15;
      pf[ks] = *(const short8*)((char*)myps +
          p_swz(qrow, qrow * 128 + ks * 64 + (lane >> 4) * 16));
    }
    // ---- O += P V (V B-frags from LDS; setprio per m191 regime) ----
    __builtin_amdgcn_s_setprio(1);
#pragma unroll
    for (int ns = 0; ns < 4; ++ns)
#pragma unroll
      for (int ks = 0; ks < 2; ++ks) {
        int row = ns * 16 + (lane & 15);   // dim within tile
        int byte = (row * 128 + ks * 64 + (lane >> 4) * 16) ^ ((row & 7) << 4);
        short8 vf = *(const short8*)(Vl + byte);
        O[ns] = __builtin_amdgcn_mfma_f32_16x16x32_bf16(pf[ks], vf, O[ns], 0, 0, 0);
      }
    __builtin_amdgcn_s_setprio(0);
    // ---- write-late: staged regs -> other buffer; single barrier ----
    if (kt + 1 < NT) {
      const int nb = cur ^ 1;
#pragma unroll
      for (int i = 0; i < 2; ++i) {
        int c = t + i * 256;
        int sw = (c * 16) ^ (((c >> 3) & 7) << 4);
        *(uint4*)((char*)&Ks[nb][0] + sw) = kreg[i];
        *(uint4*)((char*)&Vs[nb][0] + sw) = vreg[i];
      }
    }
    __syncthreads();
  }
  // ---- epilogue: normalize, write CTX [B,N,768] bf16 (head-merge fused) ----
  const int bb = bh / NH, h = bh % NH;
#pragma unroll
  for (int r = 0; r < 4; ++r) {
    float inv = 1.0f / lrun[r];
    int n = q0 + (lane >> 4) * 4 + r;
#pragma unroll
    for (int ns = 0; ns < 4; ++ns)
      CTX[((size_t)(bb * SEQ + n)) * DIN + h * DH + ns * 16 + (lane & 15)] =
          f2bf(O[ns][r] * inv);
  }
}

// ---------------------------------------------------------------------------
extern "C" void kernel_launch(void* const* d_in, const int* in_sizes, int n_in,
                              void* d_out, int out_size, void* d_ws, size_t ws_size,
                              hipStream_t stream) {
  const float* x     = (const float*)d_in[0];
  const float* w_qkv = (const float*)d_in[1];
  const float* w_out = (const float*)d_in[2];
  const float* b_out = (const float*)d_in[3];
  float* out = (float*)d_out;

  ushort* ws = (ushort*)d_ws;
  const size_t nX   = (size_t)BATCH * SEQ * DIN;     // 3,145,728
  const size_t nWq  = (size_t)DIN * QKVN;            // 1,769,472
  const size_t nWo  = (size_t)DIN * DIN;             //   589,824
  const size_t nQKV = (size_t)BATCH * NH * SEQ * DH; // 3,145,728

  ushort* xb   = ws;
  ushort* wqT  = xb + nX;
  ushort* woT  = wqT + nWq;
  ushort* Qb   = woT + nWo;
  ushort* Kb   = Qb + nQKV;
  ushort* Vt   = Kb + nQKV;
  ushort* CTX  = Vt + nQKV;   // total ~36.2 MB

  cvt_x<<<dim3(nX / 4 / 256), 256, 0, stream>>>(x, xb);
  cvt_T<<<dim3(DIN / 32, QKVN / 32), 256, 0, stream>>>(w_qkv, wqT, DIN, QKVN);
  cvt_T<<<dim3(DIN / 32, DIN / 32), 256, 0, stream>>>(w_out, woT, DIN, DIN);

  gemm_qkv<<<dim3(BATCH * SEQ / 128, QKVN / 128), 256, 0, stream>>>(
      xb, wqT, Qb, Kb, Vt);
  attn<<<dim3(SEQ / 64, BATCH * NH), 256, 0, stream>>>(Qb, Kb, Vt, CTX);
  gemm_out<<<dim3(BATCH * SEQ / 128, DIN / 128), 256, 0, stream>>>(
      CTX, woT, b_out, out);
}

// Round 8
// 210.452 us; speedup vs baseline: 1.5180x; 1.1666x over previous
//
#include <hip/hip_runtime.h>

#define SEQ   2048
#define BATCH 2
#define DIN   768
#define NH    12
#define DH    64
#define QKVN  (NH*3*DH)   /* 2304 */
#define NBH   (BATCH*NH)  /* 24 */
// Q pre-scale: attention scale folded with log2(e) -> softmax in exp2 domain.
#define QSCALE 0.18033688011112042f  /* 0.125 * log2(e) */

typedef __attribute__((ext_vector_type(8))) short short8;   // 8 bf16 = 4 VGPR
typedef __attribute__((ext_vector_type(4))) float float4v;  // MFMA acc

__device__ __forceinline__ ushort f2bf(float f) {
  union { float f; uint u; } v; v.f = f;
  return (ushort)((v.u + 0x7fffu + ((v.u >> 16) & 1u)) >> 16);  // RNE
}

// Async global->LDS, 16B per lane. LDS dest = wave-uniform base + lane*16.
__device__ __forceinline__ void gld_lds16(const void* g, void* l) {
  __builtin_amdgcn_global_load_lds(
      (__attribute__((address_space(1))) unsigned int*)(g),
      (__attribute__((address_space(3))) unsigned int*)(l), 16, 0, 0);
}

// ---------------------------------------------------------------------------
// fp32 -> bf16 straight copy (x). one float4 per thread, exact grid.
// ---------------------------------------------------------------------------
__global__ __launch_bounds__(256) void cvt_x(const float* __restrict__ X,
                                             ushort* __restrict__ Xb) {
  int i = blockIdx.x * 256 + threadIdx.x;
  float4 v = ((const float4*)X)[i];
  ushort4 o;
  o.x = f2bf(v.x); o.y = f2bf(v.y); o.z = f2bf(v.z); o.w = f2bf(v.w);
  ((ushort4*)Xb)[i] = o;
}

// ---------------------------------------------------------------------------
// fp32 [K,N] -> bf16 transposed [N,K]. 32x32 LDS tile, 256 threads.
// ---------------------------------------------------------------------------
__global__ __launch_bounds__(256) void cvt_T(const float* __restrict__ W,
                                             ushort* __restrict__ WT,
                                             int Kdim, int Ndim) {
  __shared__ float tile[32][33];
  const int tx = threadIdx.x & 31, tg = threadIdx.x >> 5;
  const int r0 = blockIdx.x * 32, c0 = blockIdx.y * 32;
#pragma unroll
  for (int i = 0; i < 4; ++i) {
    int r = tg + i * 8;
    tile[r][tx] = W[(size_t)(r0 + r) * Ndim + c0 + tx];
  }
  __syncthreads();
#pragma unroll
  for (int i = 0; i < 4; ++i) {
    int c = tg + i * 8;
    WT[(size_t)(c0 + c) * Kdim + r0 + tx] = f2bf(tile[tx][c]);
  }
}

// ---------------------------------------------------------------------------
// Shared MFMA GEMM core: C[128x128] = A[128xK] * BT[128xK]^T, K=768, BK=64.
// 4 waves (2x2), each 64x64 via 4x4 frags of 16x16x32.
// LDS in fragment order [sub(8)][ks(2)][lane(64)][8 bf16]; staged via
// global_load_lds width=16 (dest = uniform base + lane*16, layout already
// linear in staging order). Second __syncthreads drains vmcnt (m97 pattern).
// ---------------------------------------------------------------------------
#define GEMM_CORE(Abf, BT)                                                     \
  __shared__ ushort As[8192];                                                  \
  __shared__ ushort Bs[8192];                                                  \
  const int t = threadIdx.x;                                                   \
  const int lane = t & 63, wid = t >> 6;                                       \
  const int wr = wid >> 1, wc = wid & 1;                                       \
  const int m0 = blockIdx.x * 128, n0 = blockIdx.y * 128;                      \
  float4v acc[4][4] = {};                                                      \
  for (int k0 = 0; k0 < DIN; k0 += 64) {                                       \
    __syncthreads();                                                           \
    _Pragma("unroll")                                                          \
    for (int i = 0; i < 4; ++i) {                                              \
      int s   = t + i * 256;                                                   \
      int sub = s >> 7, kss = (s >> 6) & 1, l = s & 63;                        \
      int row = sub * 16 + (l & 15);                                           \
      int kc  = kss * 32 + (l >> 4) * 8;                                       \
      int lb  = (i * 256 + wid * 64) * 8;  /* wave-uniform LDS base */         \
      gld_lds16(&Abf[(size_t)(m0 + row) * DIN + k0 + kc], &As[lb]);            \
      gld_lds16(&BT[(size_t)(n0 + row) * DIN + k0 + kc], &Bs[lb]);             \
    }                                                                          \
    __syncthreads();                                                           \
    _Pragma("unroll")                                                          \
    for (int ks = 0; ks < 2; ++ks) {                                           \
      short8 a[4], b[4];                                                       \
      _Pragma("unroll")                                                        \
      for (int mi = 0; mi < 4; ++mi)                                           \
        a[mi] = *(const short8*)&As[(((wr * 4 + mi) * 2 + ks) * 64 + lane) * 8];\
      _Pragma("unroll")                                                        \
      for (int ni = 0; ni < 4; ++ni)                                           \
        b[ni] = *(const short8*)&Bs[(((wc * 4 + ni) * 2 + ks) * 64 + lane) * 8];\
      _Pragma("unroll")                                                        \
      for (int mi = 0; mi < 4; ++mi)                                           \
        _Pragma("unroll")                                                      \
        for (int ni = 0; ni < 4; ++ni)                                         \
          acc[mi][ni] = __builtin_amdgcn_mfma_f32_16x16x32_bf16(               \
              a[mi], b[ni], acc[mi][ni], 0, 0, 0);                             \
    }                                                                          \
  }

// QKV projection: epilogue scatters Q(*QSCALE),K as [BH,N,64], V as [BH,64,N].
__global__ __launch_bounds__(256) void gemm_qkv(const ushort* __restrict__ Abf,
                                                const ushort* __restrict__ BT,
                                                ushort* __restrict__ Q,
                                                ushort* __restrict__ K,
                                                ushort* __restrict__ Vt) {
  GEMM_CORE(Abf, BT)
  const int mbase = m0 + wr * 64;
#pragma unroll
  for (int ni = 0; ni < 4; ++ni) {
    // col = cbase + (lane&15); cbase 16-aligned, rem%64 in {0,16,32,48}
    // so h / which / d-block are fragment-uniform (no crossing).
    const int cbase = n0 + wc * 64 + ni * 16;
    const int h = cbase / 192, rem = cbase % 192;
    const int which = rem / 64;
    const int d0 = (rem % 64) + (lane & 15);
#pragma unroll
    for (int mi = 0; mi < 4; ++mi) {
      const int mrow = mbase + mi * 16 + (lane >> 4) * 4;
      const int bb = mrow >> 11, n = mrow & (SEQ - 1);
      const int bh = bb * NH + h;
      if (which == 2) {
        ushort4 pk;  // acc regs r=0..3 are rows n..n+3 at fixed d -> n-contig
        pk.x = f2bf(acc[mi][ni][0]); pk.y = f2bf(acc[mi][ni][1]);
        pk.z = f2bf(acc[mi][ni][2]); pk.w = f2bf(acc[mi][ni][3]);
        *(ushort4*)&Vt[((size_t)bh * DH + d0) * SEQ + n] = pk;
      } else {
        ushort* dst = (which == 0) ? Q : K;
        const float sc = (which == 0) ? QSCALE : 1.0f;
#pragma unroll
        for (int r = 0; r < 4; ++r)
          dst[((size_t)bh * SEQ + n + r) * DH + d0] = f2bf(acc[mi][ni][r] * sc);
      }
    }
  }
}

// Output projection: fp32 out + bias.
__global__ __launch_bounds__(256) void gemm_out(const ushort* __restrict__ Abf,
                                                const ushort* __restrict__ BT,
                                                const float* __restrict__ bias,
                                                float* __restrict__ Out) {
  GEMM_CORE(Abf, BT)
#pragma unroll
  for (int ni = 0; ni < 4; ++ni) {
    const int c = n0 + wc * 64 + ni * 16 + (lane & 15);
    const float bv = bias[c];
#pragma unroll
    for (int mi = 0; mi < 4; ++mi) {
      const int mrow = m0 + wr * 64 + mi * 16 + (lane >> 4) * 4;
#pragma unroll
      for (int r = 0; r < 4; ++r)
        Out[(size_t)(mrow + r) * DIN + c] = acc[mi][ni][r] + bv;
    }
  }
}

// ---------------------------------------------------------------------------
// Flash attention, bf16 MFMA, SWAPPED operands. 1D grid 768 blocks, 4 waves.
// bh = bid % 24 -> XCD c (~bid%8) sees only bh in {c,c+8,c+16}: per-XCD K/V
// footprint 1.5 MB (fits 4 MB L2); all q-tiles of a head co-locate (T1).
// S^T = mfma(K,Q): D col=lane&15=qrow -> each lane owns ONE q-row:
// softmax = 15 in-lane ops + 2 shfl steps; mrun/lrun are per-lane scalars;
// O^T = mfma(V,P^T) accumulates transposed, epilogue stores ushort4.
// K/V staged via global_load_lds with PRE-SWIZZLED SOURCE (rule 21: linear
// dest + inverse-swz source + swz on read; involution c ^= (c>>3)&7).
// Defer-max (T13): skip alpha/rescale when __all(mx <= mrun+8) (exp2 dom).
// ---------------------------------------------------------------------------
__global__ __launch_bounds__(256) void attn(const ushort* __restrict__ Q,
                                            const ushort* __restrict__ K,
                                            const ushort* __restrict__ Vt,
                                            ushort* __restrict__ CTX) {
  __shared__ ushort Ks[2][4096];  // [buf][key(64) x d(64)] swizzled, 8 KB ea
  __shared__ ushort Vs[2][4096];  // [buf][d(64) x key(64)] swizzled
  __shared__ ushort ps[4][1024];  // per-wave P 16(qrow) x 64(key), swizzled
  const int t = threadIdx.x, lane = t & 63, wid = t >> 6;
  const int lo = lane & 15, hi = lane >> 4;
  const int bid = blockIdx.x;
  const int bh = bid % NBH;       // head-major: co-locates same-bh on an XCD
  const int q0 = (bid / NBH) * 64 + wid * 16;
  const size_t base = (size_t)bh * SEQ * DH;
  const ushort* Kg = K + base;                      // [N][64] row-major
  const ushort* Vg = Vt + (size_t)bh * DH * SEQ;    // [64][N] d-major
  ushort* myps = ps[wid];

  short8 qf[2];  // frag: own-row=lo (qrow), k=ks*32+hi*8 (Q pre-scaled)
#pragma unroll
  for (int ks = 0; ks < 2; ++ks)
    qf[ks] = *(const short8*)&Q[base + (size_t)(q0 + lo) * DH + ks * 32 + hi * 8];

  float4v Ot[4] = {};               // Ot[ns][r] = O[d=ns*16+hi*4+r][qrow=lo]
  float mrun = -1e30f, lrun = 0.f;  // per-lane scalars (lane owns qrow=lo)

  // ---- prologue: async-stage tile 0 into buf 0 (source pre-swizzled) ----
#pragma unroll
  for (int i = 0; i < 2; ++i) {
    int c = t + i * 256;            // linear LDS chunk (16B units)
    int g = c ^ ((c >> 3) & 7);     // pre-swizzled source chunk
    int lb = (i * 256 + wid * 64) * 8;  // wave-uniform LDS base (ushort idx)
    gld_lds16(&Kg[g * 8], &Ks[0][lb]);
    gld_lds16(&Vg[(size_t)(g >> 3) * SEQ + (g & 7) * 8], &Vs[0][lb]);
  }
  __syncthreads();

  const int NT = SEQ / 64;
  for (int kt = 0; kt < NT; ++kt) {
    const int cur = kt & 1;
    const char* Kl = (const char*)&Ks[cur][0];
    const char* Vl = (const char*)&Vs[cur][0];
    // ---- async-stage next tile into other buffer (lands by the barrier) ----
    if (kt + 1 < NT) {
      const int key0n = (kt + 1) * 64;
#pragma unroll
      for (int i = 0; i < 2; ++i) {
        int c = t + i * 256;
        int g = c ^ ((c >> 3) & 7);
        int lb = (i * 256 + wid * 64) * 8;
        gld_lds16(&Kg[(size_t)key0n * DH + g * 8], &Ks[cur ^ 1][lb]);
        gld_lds16(&Vg[(size_t)(g >> 3) * SEQ + key0n + (g & 7) * 8],
                  &Vs[cur ^ 1][lb]);
      }
    }
    // ---- S^T = K Q^T : D col=lo=qrow, row=key(ns*16+hi*4+r) ----
    float4v st[4];
#pragma unroll
    for (int ns = 0; ns < 4; ++ns) {
      st[ns] = (float4v){0.f, 0.f, 0.f, 0.f};
#pragma unroll
      for (int ks = 0; ks < 2; ++ks) {
        int row = ns * 16 + lo;   // key (A-operand own-row)
        int byte = (row * 128 + ks * 64 + hi * 16) ^ ((row & 7) << 4);
        short8 kf = *(const short8*)(Kl + byte);
        st[ns] = __builtin_amdgcn_mfma_f32_16x16x32_bf16(kf, qf[ks], st[ns], 0, 0, 0);
      }
    }
    // ---- softmax (exp2 domain), lane-local row: in-lane tree + 2 shfl ----
    float mx = fmaxf(fmaxf(fmaxf(st[0][0], st[0][1]), fmaxf(st[0][2], st[0][3])),
                     fmaxf(fmaxf(st[1][0], st[1][1]), fmaxf(st[1][2], st[1][3])));
    mx = fmaxf(mx, fmaxf(fmaxf(fmaxf(st[2][0], st[2][1]), fmaxf(st[2][2], st[2][3])),
                         fmaxf(fmaxf(st[3][0], st[3][1]), fmaxf(st[3][2], st[3][3]))));
    mx = fmaxf(mx, __shfl_xor(mx, 16));
    mx = fmaxf(mx, __shfl_xor(mx, 32));
    if (!__all(mx <= mrun + 8.0f)) {   // defer-max: P bounded by 2^8
      float mnew  = fmaxf(mrun, mx);
      float alpha = exp2f(mrun - mnew);
      lrun *= alpha;
#pragma unroll
      for (int ns = 0; ns < 4; ++ns)
#pragma unroll
        for (int r = 0; r < 4; ++r) Ot[ns][r] *= alpha;
      mrun = mnew;
    }
    float p[4][4];
    float rs = 0.f;
#pragma unroll
    for (int ns = 0; ns < 4; ++ns)
#pragma unroll
      for (int r = 0; r < 4; ++r) {
        p[ns][r] = exp2f(st[ns][r] - mrun);
        rs += p[ns][r];
      }
    rs += __shfl_xor(rs, 16);
    rs += __shfl_xor(rs, 32);
    lrun += rs;
    // ---- P -> LDS: pack 4 consecutive keys via v_perm bf16-trunc ----
#pragma unroll
    for (int ns = 0; ns < 4; ++ns) {
      uint2 d2;
      d2.x = __builtin_amdgcn_perm(__float_as_uint(p[ns][1]),
                                   __float_as_uint(p[ns][0]), 0x07060302u);
      d2.y = __builtin_amdgcn_perm(__float_as_uint(p[ns][3]),
                                   __float_as_uint(p[ns][2]), 0x07060302u);
      int byte = (lo * 128 + ns * 32 + hi * 8) ^ ((lo & 7) << 4);
      *(uint2*)((char*)myps + byte) = d2;
    }
    // Intra-wave LDS write->read: drain explicitly (consumer is a ds_read,
    // so the "memory" clobber fully orders it).
    asm volatile("s_waitcnt lgkmcnt(0)" ::: "memory");
    // ---- P B-frags: col=qrow(lo), k=key ks*32+hi*8 contiguous-8 ----
    short8 pf[2];
#pragma unroll
    for (int ks = 0; ks < 2; ++ks) {
      int byte = (lo * 128 + ks * 64 + hi * 16) ^ ((lo & 7) << 4);
      pf[ks] = *(const short8*)((char*)myps + byte);
    }
    // ---- O^T += V^T P^T (A=vf d-rows from LDS, B=pf; setprio m191) ----
    __builtin_amdgcn_s_setprio(1);
#pragma unroll
    for (int ns = 0; ns < 4; ++ns)
#pragma unroll
      for (int ks = 0; ks < 2; ++ks) {
        int row = ns * 16 + lo;   // d (A-operand own-row)
        int byte = (row * 128 + ks * 64 + hi * 16) ^ ((row & 7) << 4);
        short8 vf = *(const short8*)(Vl + byte);
        Ot[ns] = __builtin_amdgcn_mfma_f32_16x16x32_bf16(vf, pf[ks], Ot[ns], 0, 0, 0);
      }
    __builtin_amdgcn_s_setprio(0);
    __syncthreads();  // drains gld_lds (vmcnt) + orders buffer reuse
  }
  // ---- epilogue: normalize, write CTX [B,N,768] bf16, ushort4 stores ----
  const int bb = bh / NH, h = bh % NH;
  const float inv = 1.0f / lrun;
  const int n = q0 + lo;
#pragma unroll
  for (int ns = 0; ns < 4; ++ns) {
    ushort4 o;
    o.x = f2bf(Ot[ns][0] * inv); o.y = f2bf(Ot[ns][1] * inv);
    o.z = f2bf(Ot[ns][2] * inv); o.w = f2bf(Ot[ns][3] * inv);
    *(ushort4*)&CTX[(size_t)(bb * SEQ + n) * DIN + h * DH + ns * 16 + hi * 4] = o;
  }
}

// ---------------------------------------------------------------------------
extern "C" void kernel_launch(void* const* d_in, const int* in_sizes, int n_in,
                              void* d_out, int out_size, void* d_ws, size_t ws_size,
                              hipStream_t stream) {
  const float* x     = (const float*)d_in[0];
  const float* w_qkv = (const float*)d_in[1];
  const float* w_out = (const float*)d_in[2];
  const float* b_out = (const float*)d_in[3];
  float* out = (float*)d_out;

  ushort* ws = (ushort*)d_ws;
  const size_t nX   = (size_t)BATCH * SEQ * DIN;     // 3,145,728
  const size_t nWq  = (size_t)DIN * QKVN;            // 1,769,472
  const size_t nWo  = (size_t)DIN * DIN;             //   589,824
  const size_t nQKV = (size_t)BATCH * NH * SEQ * DH; // 3,145,728

  ushort* xb   = ws;
  ushort* wqT  = xb + nX;
  ushort* woT  = wqT + nWq;
  ushort* Qb   = woT + nWo;
  ushort* Kb   = Qb + nQKV;
  ushort* Vt   = Kb + nQKV;
  ushort* CTX  = Vt + nQKV;   // total ~36.2 MB

  cvt_x<<<dim3(nX / 4 / 256), 256, 0, stream>>>(x, xb);
  cvt_T<<<dim3(DIN / 32, QKVN / 32), 256, 0, stream>>>(w_qkv, wqT, DIN, QKVN);
  cvt_T<<<dim3(DIN / 32, DIN / 32), 256, 0, stream>>>(w_out, woT, DIN, DIN);

  gemm_qkv<<<dim3(BATCH * SEQ / 128, QKVN / 128), 256, 0, stream>>>(
      xb, wqT, Qb, Kb, Vt);
  attn<<<dim3(SEQ / 64 * NBH), 256, 0, stream>>>(Qb, Kb, Vt, CTX);
  gemm_out<<<dim3(BATCH * SEQ / 128, DIN / 128), 256, 0, stream>>>(
      CTX, woT, b_out, out);
}

// Round 10
// 208.924 us; speedup vs baseline: 1.5291x; 1.0073x over previous
//
#include <hip/hip_runtime.h>

#define SEQ   2048
#define BATCH 2
#define DIN   768
#define NH    12
#define DH    64
#define QKVN  (NH*3*DH)   /* 2304 */
#define NBH   (BATCH*NH)  /* 24 */
// Q pre-scale: attention scale folded with log2(e) -> softmax in exp2 domain.
#define QSCALE 0.18033688011112042f  /* 0.125 * log2(e) */

typedef __attribute__((ext_vector_type(8))) short short8;   // 8 bf16 = 4 VGPR
typedef __attribute__((ext_vector_type(4))) float float4v;  // MFMA acc

__device__ __forceinline__ ushort f2bf(float f) {
  union { float f; uint u; } v; v.f = f;
  return (ushort)((v.u + 0x7fffu + ((v.u >> 16) & 1u)) >> 16);  // RNE
}

// Async global->LDS, 16B per lane. LDS dest = wave-uniform base + lane*16.
__device__ __forceinline__ void gld_lds16(const void* g, void* l) {
  __builtin_amdgcn_global_load_lds(
      (__attribute__((address_space(1))) unsigned int*)(g),
      (__attribute__((address_space(3))) unsigned int*)(l), 16, 0, 0);
}

// ---------------------------------------------------------------------------
// Fused converts (one dispatch, block-range dispatch):
//   blocks [0,3072):      x fp32 -> bf16 copy (float4/thread)
//   blocks [3072,4800):   w_qkv [768,2304] -> bf16 transposed [2304,768]
//   blocks [4800,5376):   w_out [768,768]  -> bf16 transposed [768,768]
// ---------------------------------------------------------------------------
__global__ __launch_bounds__(256) void cvt_all(const float* __restrict__ X,
                                               ushort* __restrict__ Xb,
                                               const float* __restrict__ Wq,
                                               ushort* __restrict__ WqT,
                                               const float* __restrict__ Wo,
                                               ushort* __restrict__ WoT) {
  __shared__ float tile[32][33];
  const int bid = blockIdx.x;
  if (bid < 3072) {  // ---- cvt_x ----
    int i = bid * 256 + threadIdx.x;
    float4 v = ((const float4*)X)[i];
    ushort4 o;
    o.x = f2bf(v.x); o.y = f2bf(v.y); o.z = f2bf(v.z); o.w = f2bf(v.w);
    ((ushort4*)Xb)[i] = o;
    return;
  }
  // ---- cvt_T ----
  const float* W; ushort* WT; int Ndim, idx;
  if (bid < 3072 + 1728) { idx = bid - 3072; W = Wq; WT = WqT; Ndim = QKVN; }
  else                   { idx = bid - 4800; W = Wo; WT = WoT; Ndim = DIN;  }
  const int bx = idx % (DIN / 32), by = idx / (DIN / 32);
  const int r0 = bx * 32, c0 = by * 32;
  const int tx = threadIdx.x & 31, tg = threadIdx.x >> 5;
#pragma unroll
  for (int i = 0; i < 4; ++i) {
    int r = tg + i * 8;
    tile[r][tx] = W[(size_t)(r0 + r) * Ndim + c0 + tx];
  }
  __syncthreads();
#pragma unroll
  for (int i = 0; i < 4; ++i) {
    int c = tg + i * 8;
    WT[(size_t)(c0 + c) * DIN + r0 + tx] = f2bf(tile[tx][c]);
  }
}

// ---------------------------------------------------------------------------
// Shared MFMA GEMM core: C[128x128] = A[128xK] * BT[128xK]^T, K=768, BK=64.
// 4 waves (2x2), each 64x64 via 4x4 frags of 16x16x32.
// LDS in fragment order [sub(8)][ks(2)][lane(64)][8 bf16]; staged via
// global_load_lds width=16 (dest = uniform base + lane*16, layout already
// linear in staging order). Second __syncthreads drains vmcnt (m97 pattern;
// docs m99/m100/m230: explicit 2-phase dbuf is null-to-negative at 128²).
// ---------------------------------------------------------------------------
#define GEMM_CORE(Abf, BT)                                                     \
  __shared__ ushort As[8192];                                                  \
  __shared__ ushort Bs[8192];                                                  \
  const int t = threadIdx.x;                                                   \
  const int lane = t & 63, wid = t >> 6;                                       \
  const int wr = wid >> 1, wc = wid & 1;                                       \
  const int m0 = blockIdx.x * 128, n0 = blockIdx.y * 128;                      \
  float4v acc[4][4] = {};                                                      \
  for (int k0 = 0; k0 < DIN; k0 += 64) {                                       \
    __syncthreads();                                                           \
    _Pragma("unroll")                                                          \
    for (int i = 0; i < 4; ++i) {                                              \
      int s   = t + i * 256;                                                   \
      int sub = s >> 7, kss = (s >> 6) & 1, l = s & 63;                        \
      int row = sub * 16 + (l & 15);                                           \
      int kc  = kss * 32 + (l >> 4) * 8;                                       \
      int lb  = (i * 256 + wid * 64) * 8;  /* wave-uniform LDS base */         \
      gld_lds16(&Abf[(size_t)(m0 + row) * DIN + k0 + kc], &As[lb]);            \
      gld_lds16(&BT[(size_t)(n0 + row) * DIN + k0 + kc], &Bs[lb]);             \
    }                                                                          \
    __syncthreads();                                                           \
    _Pragma("unroll")                                                          \
    for (int ks = 0; ks < 2; ++ks) {                                           \
      short8 a[4], b[4];                                                       \
      _Pragma("unroll")                                                        \
      for (int mi = 0; mi < 4; ++mi)                                           \
        a[mi] = *(const short8*)&As[(((wr * 4 + mi) * 2 + ks) * 64 + lane) * 8];\
      _Pragma("unroll")                                                        \
      for (int ni = 0; ni < 4; ++ni)                                           \
        b[ni] = *(const short8*)&Bs[(((wc * 4 + ni) * 2 + ks) * 64 + lane) * 8];\
      _Pragma("unroll")                                                        \
      for (int mi = 0; mi < 4; ++mi)                                           \
        _Pragma("unroll")                                                      \
        for (int ni = 0; ni < 4; ++ni)                                         \
          acc[mi][ni] = __builtin_amdgcn_mfma_f32_16x16x32_bf16(               \
              a[mi], b[ni], acc[mi][ni], 0, 0, 0);                             \
    }                                                                          \
  }

// QKV projection. Epilogue: each wave's 4 ni-frags at fixed mi form ONE
// aligned 16x64 block of a single dest (cb64 = n0+wc*64 is 64-aligned ->
// h/which uniform, d = ni*16+eL). Q/K: repack bf16 through per-wave LDS
// scratch (reuse dead As; (ni^eH) col-block swizzle, write 2 lanes/bank
// same-dword = free, read b=(lane&3)^(rr>>2) inverts it, 8 dwords/bank) ->
// global stores become contiguous 2KB/wave/mi (2x dwordx4 per lane).
// V: [bh][d][n] ushort4 scatter as before.
__global__ __launch_bounds__(256) void gemm_qkv(const ushort* __restrict__ Abf,
                                                const ushort* __restrict__ BT,
                                                ushort* __restrict__ Q,
                                                ushort* __restrict__ K,
                                                ushort* __restrict__ Vt) {
  GEMM_CORE(Abf, BT)
  __syncthreads();                       // all waves done reading As/Bs
  ushort* scr = &As[wid * 1024];         // per-wave 16x64 ushort (2 KB)
  const int eL = lane & 15, eH = lane >> 4;
  const int cb64  = n0 + wc * 64;        // aligned 64-col run
  const int h     = cb64 / 192;
  const int which = (cb64 % 192) / 64;   // uniform across ni (rem%64 == 0)
  const int mbase = m0 + wr * 64;
  if (which == 2) {
#pragma unroll
    for (int ni = 0; ni < 4; ++ni) {
      const int d0 = ni * 16 + eL;
#pragma unroll
      for (int mi = 0; mi < 4; ++mi) {
        const int mrow = mbase + mi * 16 + eH * 4;
        const int bb = mrow >> 11, n = mrow & (SEQ - 1);
        const int bhv = bb * NH + h;
        ushort4 pk;  // acc regs r=0..3 are rows n..n+3 at fixed d -> n-contig
        pk.x = f2bf(acc[mi][ni][0]); pk.y = f2bf(acc[mi][ni][1]);
        pk.z = f2bf(acc[mi][ni][2]); pk.w = f2bf(acc[mi][ni][3]);
        *(ushort4*)&Vt[((size_t)bhv * DH + d0) * SEQ + n] = pk;
      }
    }
  } else {
    ushort* dst = (which == 0) ? Q : K;
    const float sc = (which == 0) ? QSCALE : 1.0f;
    const int rr = lane >> 2;                 // read-back row
    const int rb = (lane & 3) ^ (rr >> 2);    // de-swizzled col block
    const int roff = rr * 64 + rb * 16;       // 32B-aligned
#pragma unroll
    for (int mi = 0; mi < 4; ++mi) {
      const int mrow = mbase + mi * 16;       // 16-aligned, can't cross batch
      const int bb = mrow >> 11, nb = mrow & (SEQ - 1);
#pragma unroll
      for (int ni = 0; ni < 4; ++ni) {
        const int sb = ((ni ^ eH) & 3) * 16;  // swizzled col-block
#pragma unroll
        for (int r = 0; r < 4; ++r)
          scr[(eH * 4 + r) * 64 + sb + eL] = f2bf(acc[mi][ni][r] * sc);
      }
      asm volatile("s_waitcnt lgkmcnt(0)" ::: "memory");  // wave-local RAW
      short8 v0 = *(const short8*)&scr[roff];
      short8 v1 = *(const short8*)&scr[roff + 8];
      ushort* gp = dst + ((size_t)(bb * NH + h) * SEQ + nb) * DH + lane * 16;
      *(short8*)&gp[0] = v0;
      *(short8*)&gp[8] = v1;
      asm volatile("s_waitcnt lgkmcnt(0)" ::: "memory");  // reads before reuse
    }
  }
}

// Output projection: fp32 out + bias.
__global__ __launch_bounds__(256) void gemm_out(const ushort* __restrict__ Abf,
                                                const ushort* __restrict__ BT,
                                                const float* __restrict__ bias,
                                                float* __restrict__ Out) {
  GEMM_CORE(Abf, BT)
#pragma unroll
  for (int ni = 0; ni < 4; ++ni) {
    const int c = n0 + wc * 64 + ni * 16 + (lane & 15);
    const float bv = bias[c];
#pragma unroll
    for (int mi = 0; mi < 4; ++mi) {
      const int mrow = m0 + wr * 64 + mi * 16 + (lane >> 4) * 4;
#pragma unroll
      for (int r = 0; r < 4; ++r)
        Out[(size_t)(mrow + r) * DIN + c] = acc[mi][ni][r] + bv;
    }
  }
}

// ---------------------------------------------------------------------------
// Flash attention, bf16 MFMA, SWAPPED operands. 1D grid 768 blocks, 4 waves.
// bh = bid % 24 -> XCD c sees only bh in {c,c+8,c+16} (T1; R8: FETCH 52->9MB).
// R8 was latency-bound (MfmaUtil 14%, occupancy grid-capped): all loop-
// invariant swizzled LDS offsets (14) and staging pointers (4) HOISTED out of
// the kt loop (VGPR 56->~90, still 3 waves/SIMD at the cap) to cut per-iter
// address VALU and chain setup.
// K/V staged via global_load_lds with PRE-SWIZZLED SOURCE (rule 21: linear
// dest + inverse-swz source + swz on read; involution c ^= (c>>3)&7).
// Defer-max (T13): skip alpha/rescale when __all(mx <= mrun+8) (exp2 dom).
// ---------------------------------------------------------------------------
__global__ __launch_bounds__(256) void attn(const ushort* __restrict__ Q,
                                            const ushort* __restrict__ K,
                                            const ushort* __restrict__ Vt,
                                            ushort* __restrict__ CTX) {
  __shared__ ushort Ks[2][4096];  // [buf][key(64) x d(64)] swizzled, 8 KB ea
  __shared__ ushort Vs[2][4096];  // [buf][d(64) x key(64)] swizzled
  __shared__ ushort ps[4][1024];  // per-wave P 16(qrow) x 64(key), swizzled
  const int t = threadIdx.x, lane = t & 63, wid = t >> 6;
  const int lo = lane & 15, hi = lane >> 4;
  const int bid = blockIdx.x;
  const int bh = bid % NBH;       // head-major: co-locates same-bh on an XCD
  const int q0 = (bid / NBH) * 64 + wid * 16;
  const size_t base = (size_t)bh * SEQ * DH;
  ushort* myps = ps[wid];

  // ---- hoisted loop-invariant LDS byte offsets (static idx -> registers) ----
  int kvoff[4][2];  // K-frag and V-frag share the formula (same row, ks)
#pragma unroll
  for (int ns = 0; ns < 4; ++ns)
#pragma unroll
    for (int ks = 0; ks < 2; ++ks) {
      int row = ns * 16 + lo;
      kvoff[ns][ks] = (row * 128 + ks * 64 + hi * 16) ^ ((row & 7) << 4);
    }
  int pwoff[4], proff[2];
#pragma unroll
  for (int ns = 0; ns < 4; ++ns)
    pwoff[ns] = (lo * 128 + ns * 32 + hi * 8) ^ ((lo & 7) << 4);
#pragma unroll
  for (int ks = 0; ks < 2; ++ks)
    proff[ks] = (lo * 128 + ks * 64 + hi * 16) ^ ((lo & 7) << 4);

  // ---- hoisted staging pointers (advance one tile per iteration) ----
  const int c0i = t, c1i = t + 256;
  const int g0 = c0i ^ ((c0i >> 3) & 7), g1 = c1i ^ ((c1i >> 3) & 7);
  const int lb0 = (wid * 64) * 8, lb1 = (256 + wid * 64) * 8;
  const ushort* kp0 = K + base + g0 * 8;
  const ushort* kp1 = K + base + g1 * 8;
  const ushort* vp0 = Vt + (size_t)bh * DH * SEQ + (size_t)(g0 >> 3) * SEQ + (g0 & 7) * 8;
  const ushort* vp1 = Vt + (size_t)bh * DH * SEQ + (size_t)(g1 >> 3) * SEQ + (g1 & 7) * 8;

  short8 qf[2];  // frag: own-row=lo (qrow), k=ks*32+hi*8 (Q pre-scaled)
#pragma unroll
  for (int ks = 0; ks < 2; ++ks)
    qf[ks] = *(const short8*)&Q[base + (size_t)(q0 + lo) * DH + ks * 32 + hi * 8];

  float4v Ot[4] = {};               // Ot[ns][r] = O[d=ns*16+hi*4+r][qrow=lo]
  float mrun = -1e30f, lrun = 0.f;  // per-lane scalars (lane owns qrow=lo)

  // ---- prologue: async-stage tile 0 into buf 0 ----
  gld_lds16(kp0, &Ks[0][lb0]);
  gld_lds16(kp1, &Ks[0][lb1]);
  gld_lds16(vp0, &Vs[0][lb0]);
  gld_lds16(vp1, &Vs[0][lb1]);
  kp0 += 64 * DH; kp1 += 64 * DH; vp0 += 64; vp1 += 64;
  __syncthreads();

  const int NT = SEQ / 64;
  for (int kt = 0; kt < NT; ++kt) {
    const int cur = kt & 1, nb = cur ^ 1;
    const char* Kl = (const char*)&Ks[cur][0];
    const char* Vl = (const char*)&Vs[cur][0];
    // ---- async-stage next tile into other buffer (lands by the barrier) ----
    if (kt + 1 < NT) {
      gld_lds16(kp0, &Ks[nb][lb0]);
      gld_lds16(kp1, &Ks[nb][lb1]);
      gld_lds16(vp0, &Vs[nb][lb0]);
      gld_lds16(vp1, &Vs[nb][lb1]);
      kp0 += 64 * DH; kp1 += 64 * DH; vp0 += 64; vp1 += 64;
    }
    // ---- S^T = K Q^T : D col=lo=qrow, row=key(ns*16+hi*4+r) ----
    float4v st[4];
#pragma unroll
    for (int ns = 0; ns < 4; ++ns) {
      st[ns] = (float4v){0.f, 0.f, 0.f, 0.f};
#pragma unroll
      for (int ks = 0; ks < 2; ++ks) {
        short8 kf = *(const short8*)(Kl + kvoff[ns][ks]);
        st[ns] = __builtin_amdgcn_mfma_f32_16x16x32_bf16(kf, qf[ks], st[ns], 0, 0, 0);
      }
    }
    // ---- softmax (exp2 domain), lane-local row: in-lane tree + 2 shfl ----
    float mx = fmaxf(fmaxf(fmaxf(st[0][0], st[0][1]), fmaxf(st[0][2], st[0][3])),
                     fmaxf(fmaxf(st[1][0], st[1][1]), fmaxf(st[1][2], st[1][3])));
    mx = fmaxf(mx, fmaxf(fmaxf(fmaxf(st[2][0], st[2][1]), fmaxf(st[2][2], st[2][3])),
                         fmaxf(fmaxf(st[3][0], st[3][1]), fmaxf(st[3][2], st[3][3]))));
    mx = fmaxf(mx, __shfl_xor(mx, 16));
    mx = fmaxf(mx, __shfl_xor(mx, 32));
    if (!__all(mx <= mrun + 8.0f)) {   // defer-max: P bounded by 2^8
      float mnew  = fmaxf(mrun, mx);
      float alpha = exp2f(mrun - mnew);
      lrun *= alpha;
#pragma unroll
      for (int ns = 0; ns < 4; ++ns)
#pragma unroll
        for (int r = 0; r < 4; ++r) Ot[ns][r] *= alpha;
      mrun = mnew;
    }
    float p[4][4];
    float rs = 0.f;
#pragma unroll
    for (int ns = 0; ns < 4; ++ns)
#pragma unroll
      for (int r = 0; r < 4; ++r) {
        p[ns][r] = exp2f(st[ns][r] - mrun);
        rs += p[ns][r];
      }
    rs += __shfl_xor(rs, 16);
    rs += __shfl_xor(rs, 32);
    lrun += rs;
    // ---- P -> LDS: pack 4 consecutive keys via v_perm bf16-trunc ----
#pragma unroll
    for (int ns = 0; ns < 4; ++ns) {
      uint2 d2;
      d2.x = __builtin_amdgcn_perm(__float_as_uint(p[ns][1]),
                                   __float_as_uint(p[ns][0]), 0x07060302u);
      d2.y = __builtin_amdgcn_perm(__float_as_uint(p[ns][3]),
                                   __float_as_uint(p[ns][2]), 0x07060302u);
      *(uint2*)((char*)myps + pwoff[ns]) = d2;
    }
    // Intra-wave LDS write->read: drain explicitly (consumer is a ds_read,
    // so the "memory" clobber fully orders it).
    asm volatile("s_waitcnt lgkmcnt(0)" ::: "memory");
    // ---- P B-frags: col=qrow(lo), k=key ks*32+hi*8 contiguous-8 ----
    short8 pf[2];
#pragma unroll
    for (int ks = 0; ks < 2; ++ks)
      pf[ks] = *(const short8*)((char*)myps + proff[ks]);
    // ---- O^T += V^T P^T (A=vf d-rows from LDS, B=pf; setprio m191) ----
    __builtin_amdgcn_s_setprio(1);
#pragma unroll
    for (int ns = 0; ns < 4; ++ns)
#pragma unroll
      for (int ks = 0; ks < 2; ++ks) {
        short8 vf = *(const short8*)(Vl + kvoff[ns][ks]);
        Ot[ns] = __builtin_amdgcn_mfma_f32_16x16x32_bf16(vf, pf[ks], Ot[ns], 0, 0, 0);
      }
    __builtin_amdgcn_s_setprio(0);
    __syncthreads();  // drains gld_lds (vmcnt) + orders buffer reuse
  }
  // ---- epilogue: normalize, write CTX [B,N,768] bf16, ushort4 stores ----
  const int bb = bh / NH, h = bh % NH;
  const float inv = 1.0f / lrun;
  const int n = q0 + lo;
#pragma unroll
  for (int ns = 0; ns < 4; ++ns) {
    ushort4 o;
    o.x = f2bf(Ot[ns][0] * inv); o.y = f2bf(Ot[ns][1] * inv);
    o.z = f2bf(Ot[ns][2] * inv); o.w = f2bf(Ot[ns][3] * inv);
    *(ushort4*)&CTX[(size_t)(bb * SEQ + n) * DIN + h * DH + ns * 16 + hi * 4] = o;
  }
}

// ---------------------------------------------------------------------------
extern "C" void kernel_launch(void* const* d_in, const int* in_sizes, int n_in,
                              void* d_out, int out_size, void* d_ws, size_t ws_size,
                              hipStream_t stream) {
  const float* x     = (const float*)d_in[0];
  const float* w_qkv = (const float*)d_in[1];
  const float* w_out = (const float*)d_in[2];
  const float* b_out = (const float*)d_in[3];
  float* out = (float*)d_out;

  ushort* ws = (ushort*)d_ws;
  const size_t nX   = (size_t)BATCH * SEQ * DIN;     // 3,145,728
  const size_t nWq  = (size_t)DIN * QKVN;            // 1,769,472
  const size_t nWo  = (size_t)DIN * DIN;             //   589,824
  const size_t nQKV = (size_t)BATCH * NH * SEQ * DH; // 3,145,728

  ushort* xb   = ws;
  ushort* wqT  = xb + nX;
  ushort* woT  = wqT + nWq;
  ushort* Qb   = woT + nWo;
  ushort* Kb   = Qb + nQKV;
  ushort* Vt   = Kb + nQKV;
  ushort* CTX  = Vt + nQKV;   // total ~36.2 MB

  cvt_all<<<dim3(5376), 256, 0, stream>>>(x, xb, w_qkv, wqT, w_out, woT);
  gemm_qkv<<<dim3(BATCH * SEQ / 128, QKVN / 128), 256, 0, stream>>>(
      xb, wqT, Qb, Kb, Vt);
  attn<<<dim3(SEQ / 64 * NBH), 256, 0, stream>>>(Qb, Kb, Vt, CTX);
  gemm_out<<<dim3(BATCH * SEQ / 128, DIN / 128), 256, 0, stream>>>(
      CTX, woT, b_out, out);
}

// Round 12
// 187.890 us; speedup vs baseline: 1.7003x; 1.1119x over previous
//
#include <hip/hip_runtime.h>

#define SEQ   2048
#define BATCH 2
#define DIN   768
#define NH    12
#define DH    64
#define QKVN  (NH*3*DH)   /* 2304 */
#define NBH   (BATCH*NH)  /* 24 */
// Q pre-scale: attention scale folded with log2(e) -> softmax in exp2 domain.
#define QSCALE 0.18033688011112042f  /* 0.125 * log2(e) */

typedef __attribute__((ext_vector_type(8))) short short8;   // 8 bf16 = 4 VGPR
typedef __attribute__((ext_vector_type(4))) float float4v;  // MFMA acc

__device__ __forceinline__ ushort f2bf(float f) {
  union { float f; uint u; } v; v.f = f;
  return (ushort)((v.u + 0x7fffu + ((v.u >> 16) & 1u)) >> 16);  // RNE
}

// Raw hardware exp2 / rcp (1 instr; ocml exp2f is a multi-instr guarded seq).
// Inputs bounded: exp args <= +8 (defer-max), very-negative -> 0 in HW.
// gfx9-lineage VALU (incl. TRANS) is HW-interlocked; asm constraint carries
// the register dependency, so no explicit wait states are needed.
__device__ __forceinline__ float fexp2(float x) {
  float r; asm("v_exp_f32 %0, %1" : "=v"(r) : "v"(x)); return r;
}
__device__ __forceinline__ float frcp(float x) {
  float r; asm("v_rcp_f32 %0, %1" : "=v"(r) : "v"(x)); return r;
}

// Async global->LDS, 16B per lane. LDS dest = wave-uniform base + lane*16.
__device__ __forceinline__ void gld_lds16(const void* g, void* l) {
  __builtin_amdgcn_global_load_lds(
      (__attribute__((address_space(1))) unsigned int*)(g),
      (__attribute__((address_space(3))) unsigned int*)(l), 16, 0, 0);
}

// ---------------------------------------------------------------------------
// Fused converts (one dispatch, block-range dispatch):
//   blocks [0,3072):      x fp32 -> bf16 copy (float4/thread)
//   blocks [3072,4800):   w_qkv [768,2304] -> bf16 transposed [2304,768]
//   blocks [4800,5376):   w_out [768,768]  -> bf16 transposed [768,768]
// ---------------------------------------------------------------------------
__global__ __launch_bounds__(256) void cvt_all(const float* __restrict__ X,
                                               ushort* __restrict__ Xb,
                                               const float* __restrict__ Wq,
                                               ushort* __restrict__ WqT,
                                               const float* __restrict__ Wo,
                                               ushort* __restrict__ WoT) {
  __shared__ float tile[32][33];
  const int bid = blockIdx.x;
  if (bid < 3072) {  // ---- cvt_x ----
    int i = bid * 256 + threadIdx.x;
    float4 v = ((const float4*)X)[i];
    ushort4 o;
    o.x = f2bf(v.x); o.y = f2bf(v.y); o.z = f2bf(v.z); o.w = f2bf(v.w);
    ((ushort4*)Xb)[i] = o;
    return;
  }
  // ---- cvt_T ----
  const float* W; ushort* WT; int Ndim, idx;
  if (bid < 3072 + 1728) { idx = bid - 3072; W = Wq; WT = WqT; Ndim = QKVN; }
  else                   { idx = bid - 4800; W = Wo; WT = WoT; Ndim = DIN;  }
  const int bx = idx % (DIN / 32), by = idx / (DIN / 32);
  const int r0 = bx * 32, c0 = by * 32;
  const int tx = threadIdx.x & 31, tg = threadIdx.x >> 5;
#pragma unroll
  for (int i = 0; i < 4; ++i) {
    int r = tg + i * 8;
    tile[r][tx] = W[(size_t)(r0 + r) * Ndim + c0 + tx];
  }
  __syncthreads();
#pragma unroll
  for (int i = 0; i < 4; ++i) {
    int c = tg + i * 8;
    WT[(size_t)(c0 + c) * DIN + r0 + tx] = f2bf(tile[tx][c]);
  }
}

// ---------------------------------------------------------------------------
// MFMA GEMM core, 128x128 tile (gemm_qkv): 4 waves (2x2), each 64x64 via
// 4x4 frags of 16x16x32. LDS fragment order [sub(8)][ks(2)][lane(64)][8];
// staged via global_load_lds width=16. Barrier drains vmcnt (m97 pattern).
// ---------------------------------------------------------------------------
#define GEMM_CORE(Abf, BT)                                                     \
  __shared__ ushort As[8192];                                                  \
  __shared__ ushort Bs[8192];                                                  \
  const int t = threadIdx.x;                                                   \
  const int lane = t & 63, wid = t >> 6;                                       \
  const int wr = wid >> 1, wc = wid & 1;                                       \
  const int m0 = blockIdx.x * 128, n0 = blockIdx.y * 128;                      \
  float4v acc[4][4] = {};                                                      \
  for (int k0 = 0; k0 < DIN; k0 += 64) {                                       \
    __syncthreads();                                                           \
    _Pragma("unroll")                                                          \
    for (int i = 0; i < 4; ++i) {                                              \
      int s   = t + i * 256;                                                   \
      int sub = s >> 7, kss = (s >> 6) & 1, l = s & 63;                        \
      int row = sub * 16 + (l & 15);                                           \
      int kc  = kss * 32 + (l >> 4) * 8;                                       \
      int lb  = (i * 256 + wid * 64) * 8;  /* wave-uniform LDS base */         \
      gld_lds16(&Abf[(size_t)(m0 + row) * DIN + k0 + kc], &As[lb]);            \
      gld_lds16(&BT[(size_t)(n0 + row) * DIN + k0 + kc], &Bs[lb]);             \
    }                                                                          \
    __syncthreads();                                                           \
    _Pragma("unroll")                                                          \
    for (int ks = 0; ks < 2; ++ks) {                                           \
      short8 a[4], b[4];                                                       \
      _Pragma("unroll")                                                        \
      for (int mi = 0; mi < 4; ++mi)                                           \
        a[mi] = *(const short8*)&As[(((wr * 4 + mi) * 2 + ks) * 64 + lane) * 8];\
      _Pragma("unroll")                                                        \
      for (int ni = 0; ni < 4; ++ni)                                           \
        b[ni] = *(const short8*)&Bs[(((wc * 4 + ni) * 2 + ks) * 64 + lane) * 8];\
      _Pragma("unroll")                                                        \
      for (int mi = 0; mi < 4; ++mi)                                           \
        _Pragma("unroll")                                                      \
        for (int ni = 0; ni < 4; ++ni)                                         \
          acc[mi][ni] = __builtin_amdgcn_mfma_f32_16x16x32_bf16(               \
              a[mi], b[ni], acc[mi][ni], 0, 0, 0);                             \
    }                                                                          \
  }

// QKV projection. Epilogue: each wave's 4 ni-frags at fixed mi form ONE
// aligned 16x64 block of a single dest (cb64 = n0+wc*64 is 64-aligned ->
// h/which uniform, d = ni*16+eL). Q/K: repack bf16 through per-wave LDS
// scratch (reuse dead As; (ni^eH) col-block swizzle, write 2 lanes/bank
// same-dword = free, read b=(lane&3)^(rr>>2) inverts it, 8 dwords/bank) ->
// global stores become contiguous 2KB/wave/mi (2x dwordx4 per lane).
// V: [bh][d][n] ushort4 scatter as before.
__global__ __launch_bounds__(256) void gemm_qkv(const ushort* __restrict__ Abf,
                                                const ushort* __restrict__ BT,
                                                ushort* __restrict__ Q,
                                                ushort* __restrict__ K,
                                                ushort* __restrict__ Vt) {
  GEMM_CORE(Abf, BT)
  __syncthreads();                       // all waves done reading As/Bs
  ushort* scr = &As[wid * 1024];         // per-wave 16x64 ushort (2 KB)
  const int eL = lane & 15, eH = lane >> 4;
  const int cb64  = n0 + wc * 64;        // aligned 64-col run
  const int h     = cb64 / 192;
  const int which = (cb64 % 192) / 64;   // uniform across ni (rem%64 == 0)
  const int mbase = m0 + wr * 64;
  if (which == 2) {
#pragma unroll
    for (int ni = 0; ni < 4; ++ni) {
      const int d0 = ni * 16 + eL;
#pragma unroll
      for (int mi = 0; mi < 4; ++mi) {
        const int mrow = mbase + mi * 16 + eH * 4;
        const int bb = mrow >> 11, n = mrow & (SEQ - 1);
        const int bhv = bb * NH + h;
        ushort4 pk;  // acc regs r=0..3 are rows n..n+3 at fixed d -> n-contig
        pk.x = f2bf(acc[mi][ni][0]); pk.y = f2bf(acc[mi][ni][1]);
        pk.z = f2bf(acc[mi][ni][2]); pk.w = f2bf(acc[mi][ni][3]);
        *(ushort4*)&Vt[((size_t)bhv * DH + d0) * SEQ + n] = pk;
      }
    }
  } else {
    ushort* dst = (which == 0) ? Q : K;
    const float sc = (which == 0) ? QSCALE : 1.0f;
    const int rr = lane >> 2;                 // read-back row
    const int rb = (lane & 3) ^ (rr >> 2);    // de-swizzled col block
    const int roff = rr * 64 + rb * 16;       // 32B-aligned
#pragma unroll
    for (int mi = 0; mi < 4; ++mi) {
      const int mrow = mbase + mi * 16;       // 16-aligned, can't cross batch
      const int bb = mrow >> 11, nb = mrow & (SEQ - 1);
#pragma unroll
      for (int ni = 0; ni < 4; ++ni) {
        const int sb = ((ni ^ eH) & 3) * 16;  // swizzled col-block
#pragma unroll
        for (int r = 0; r < 4; ++r)
          scr[(eH * 4 + r) * 64 + sb + eL] = f2bf(acc[mi][ni][r] * sc);
      }
      asm volatile("s_waitcnt lgkmcnt(0)" ::: "memory");  // wave-local RAW
      short8 v0 = *(const short8*)&scr[roff];
      short8 v1 = *(const short8*)&scr[roff + 8];
      ushort* gp = dst + ((size_t)(bb * NH + h) * SEQ + nb) * DH + lane * 16;
      *(short8*)&gp[0] = v0;
      *(short8*)&gp[8] = v1;
      asm volatile("s_waitcnt lgkmcnt(0)" ::: "memory");  // reads before reuse
    }
  }
}

// ---------------------------------------------------------------------------
// Output projection, 64x64 tile: at 128x128 this GEMM ran 192 blocks =
// 1 block/CU = 1 wave/SIMD (zero latency hiding). 64x64 -> 768 blocks = 3/CU.
// 4 waves (2x2), each 32x32 via 2x2 frags. Same chunk-identity staging:
// chunk s = sub*128 + kss*64 + l  ==  read chunk (sub*2+ks)*64 + lane.
// ---------------------------------------------------------------------------
__global__ __launch_bounds__(256) void gemm_out(const ushort* __restrict__ Abf,
                                                const ushort* __restrict__ BT,
                                                const float* __restrict__ bias,
                                                float* __restrict__ Out) {
  __shared__ ushort As[4096];
  __shared__ ushort Bs[4096];
  const int t = threadIdx.x;
  const int lane = t & 63, wid = t >> 6;
  const int wr = wid >> 1, wc = wid & 1;
  const int m0 = blockIdx.x * 64, n0 = blockIdx.y * 64;
  float4v acc[2][2] = {};
  for (int k0 = 0; k0 < DIN; k0 += 64) {
    __syncthreads();
#pragma unroll
    for (int i = 0; i < 2; ++i) {
      int s   = t + i * 256;              // 0..511
      int sub = s >> 7, kss = (s >> 6) & 1, l = s & 63;
      int row = sub * 16 + (l & 15);
      int kc  = kss * 32 + (l >> 4) * 8;
      int lb  = (i * 256 + wid * 64) * 8;
      gld_lds16(&Abf[(size_t)(m0 + row) * DIN + k0 + kc], &As[lb]);
      gld_lds16(&BT[(size_t)(n0 + row) * DIN + k0 + kc], &Bs[lb]);
    }
    __syncthreads();
#pragma unroll
    for (int ks = 0; ks < 2; ++ks) {
      short8 a[2], b[2];
#pragma unroll
      for (int mi = 0; mi < 2; ++mi)
        a[mi] = *(const short8*)&As[(((wr * 2 + mi) * 2 + ks) * 64 + lane) * 8];
#pragma unroll
      for (int ni = 0; ni < 2; ++ni)
        b[ni] = *(const short8*)&Bs[(((wc * 2 + ni) * 2 + ks) * 64 + lane) * 8];
#pragma unroll
      for (int mi = 0; mi < 2; ++mi)
#pragma unroll
        for (int ni = 0; ni < 2; ++ni)
          acc[mi][ni] = __builtin_amdgcn_mfma_f32_16x16x32_bf16(
              a[mi], b[ni], acc[mi][ni], 0, 0, 0);
    }
  }
#pragma unroll
  for (int ni = 0; ni < 2; ++ni) {
    const int c = n0 + wc * 32 + ni * 16 + (lane & 15);
    const float bv = bias[c];
#pragma unroll
    for (int mi = 0; mi < 2; ++mi) {
      const int mrow = m0 + wr * 32 + mi * 16 + (lane >> 4) * 4;
#pragma unroll
      for (int r = 0; r < 4; ++r)
        Out[(size_t)(mrow + r) * DIN + c] = acc[mi][ni][r] + bv;
    }
  }
}

// ---------------------------------------------------------------------------
// Flash attention, bf16 MFMA, SWAPPED operands. 1D grid 768 blocks, 4 waves.
// bh = bid % 24 -> XCD c sees only bh in {c,c+8,c+16} (T1; FETCH 52->9MB).
// R10 lesson: VGPR stayed 56 (regalloc rematerialized the hoisted offsets)
// and exp2f is a multi-instr ocml sequence. Fix: __launch_bounds__(256,3)
// (grid caps at 3 blocks/CU anyway -> VGPR budget ~170, hoists stick) and
// raw v_exp_f32 / v_rcp_f32 inline asm.
// K/V staged via global_load_lds with PRE-SWIZZLED SOURCE (rule 21: linear
// dest + inverse-swz source + swz on read; involution c ^= (c>>3)&7).
// Defer-max (T13): skip alpha/rescale when __all(mx <= mrun+8) (exp2 dom).
// ---------------------------------------------------------------------------
__global__ __launch_bounds__(256, 3) void attn(const ushort* __restrict__ Q,
                                               const ushort* __restrict__ K,
                                               const ushort* __restrict__ Vt,
                                               ushort* __restrict__ CTX) {
  __shared__ ushort Ks[2][4096];  // [buf][key(64) x d(64)] swizzled, 8 KB ea
  __shared__ ushort Vs[2][4096];  // [buf][d(64) x key(64)] swizzled
  __shared__ ushort ps[4][1024];  // per-wave P 16(qrow) x 64(key), swizzled
  const int t = threadIdx.x, lane = t & 63, wid = t >> 6;
  const int lo = lane & 15, hi = lane >> 4;
  const int bid = blockIdx.x;
  const int bh = bid % NBH;       // head-major: co-locates same-bh on an XCD
  const int q0 = (bid / NBH) * 64 + wid * 16;
  const size_t base = (size_t)bh * SEQ * DH;
  ushort* myps = ps[wid];

  // ---- hoisted loop-invariant LDS byte offsets (static idx -> registers) ----
  int kvoff[4][2];  // K-frag and V-frag share the formula (same row, ks)
#pragma unroll
  for (int ns = 0; ns < 4; ++ns)
#pragma unroll
    for (int ks = 0; ks < 2; ++ks) {
      int row = ns * 16 + lo;
      kvoff[ns][ks] = (row * 128 + ks * 64 + hi * 16) ^ ((row & 7) << 4);
    }
  int pwoff[4], proff[2];
#pragma unroll
  for (int ns = 0; ns < 4; ++ns)
    pwoff[ns] = (lo * 128 + ns * 32 + hi * 8) ^ ((lo & 7) << 4);
#pragma unroll
  for (int ks = 0; ks < 2; ++ks)
    proff[ks] = (lo * 128 + ks * 64 + hi * 16) ^ ((lo & 7) << 4);

  // ---- hoisted staging pointers (advance one tile per iteration) ----
  const int c0i = t, c1i = t + 256;
  const int g0 = c0i ^ ((c0i >> 3) & 7), g1 = c1i ^ ((c1i >> 3) & 7);
  const int lb0 = (wid * 64) * 8, lb1 = (256 + wid * 64) * 8;
  const ushort* kp0 = K + base + g0 * 8;
  const ushort* kp1 = K + base + g1 * 8;
  const ushort* vp0 = Vt + (size_t)bh * DH * SEQ + (size_t)(g0 >> 3) * SEQ + (g0 & 7) * 8;
  const ushort* vp1 = Vt + (size_t)bh * DH * SEQ + (size_t)(g1 >> 3) * SEQ + (g1 & 7) * 8;

  short8 qf[2];  // frag: own-row=lo (qrow), k=ks*32+hi*8 (Q pre-scaled)
#pragma unroll
  for (int ks = 0; ks < 2; ++ks)
    qf[ks] = *(const short8*)&Q[base + (size_t)(q0 + lo) * DH + ks * 32 + hi * 8];

  float4v Ot[4] = {};               // Ot[ns][r] = O[d=ns*16+hi*4+r][qrow=lo]
  float mrun = -1e30f, lrun = 0.f;  // per-lane scalars (lane owns qrow=lo)

  // ---- prologue: async-stage tile 0 into buf 0 ----
  gld_lds16(kp0, &Ks[0][lb0]);
  gld_lds16(kp1, &Ks[0][lb1]);
  gld_lds16(vp0, &Vs[0][lb0]);
  gld_lds16(vp1, &Vs[0][lb1]);
  kp0 += 64 * DH; kp1 += 64 * DH; vp0 += 64; vp1 += 64;
  __syncthreads();

  const int NT = SEQ / 64;
  for (int kt = 0; kt < NT; ++kt) {
    const int cur = kt & 1, nb = cur ^ 1;
    const char* Kl = (const char*)&Ks[cur][0];
    const char* Vl = (const char*)&Vs[cur][0];
    // ---- async-stage next tile into other buffer (lands by the barrier) ----
    if (kt + 1 < NT) {
      gld_lds16(kp0, &Ks[nb][lb0]);
      gld_lds16(kp1, &Ks[nb][lb1]);
      gld_lds16(vp0, &Vs[nb][lb0]);
      gld_lds16(vp1, &Vs[nb][lb1]);
      kp0 += 64 * DH; kp1 += 64 * DH; vp0 += 64; vp1 += 64;
    }
    // ---- S^T = K Q^T : D col=lo=qrow, row=key(ns*16+hi*4+r) ----
    float4v st[4];
#pragma unroll
    for (int ns = 0; ns < 4; ++ns) {
      st[ns] = (float4v){0.f, 0.f, 0.f, 0.f};
#pragma unroll
      for (int ks = 0; ks < 2; ++ks) {
        short8 kf = *(const short8*)(Kl + kvoff[ns][ks]);
        st[ns] = __builtin_amdgcn_mfma_f32_16x16x32_bf16(kf, qf[ks], st[ns], 0, 0, 0);
      }
    }
    // ---- softmax (exp2 domain), lane-local row: in-lane tree + 2 shfl ----
    float mx = fmaxf(fmaxf(fmaxf(st[0][0], st[0][1]), fmaxf(st[0][2], st[0][3])),
                     fmaxf(fmaxf(st[1][0], st[1][1]), fmaxf(st[1][2], st[1][3])));
    mx = fmaxf(mx, fmaxf(fmaxf(fmaxf(st[2][0], st[2][1]), fmaxf(st[2][2], st[2][3])),
                         fmaxf(fmaxf(st[3][0], st[3][1]), fmaxf(st[3][2], st[3][3]))));
    mx = fmaxf(mx, __shfl_xor(mx, 16));
    mx = fmaxf(mx, __shfl_xor(mx, 32));
    if (!__all(mx <= mrun + 8.0f)) {   // defer-max: P bounded by 2^8
      float mnew  = fmaxf(mrun, mx);
      float alpha = fexp2(mrun - mnew);
      lrun *= alpha;
#pragma unroll
      for (int ns = 0; ns < 4; ++ns)
#pragma unroll
        for (int r = 0; r < 4; ++r) Ot[ns][r] *= alpha;
      mrun = mnew;
    }
    float p[4][4];
    float rs = 0.f;
#pragma unroll
    for (int ns = 0; ns < 4; ++ns)
#pragma unroll
      for (int r = 0; r < 4; ++r) {
        p[ns][r] = fexp2(st[ns][r] - mrun);
        rs += p[ns][r];
      }
    rs += __shfl_xor(rs, 16);
    rs += __shfl_xor(rs, 32);
    lrun += rs;
    // ---- P -> LDS: pack 4 consecutive keys via v_perm bf16-trunc ----
#pragma unroll
    for (int ns = 0; ns < 4; ++ns) {
      uint2 d2;
      d2.x = __builtin_amdgcn_perm(__float_as_uint(p[ns][1]),
                                   __float_as_uint(p[ns][0]), 0x07060302u);
      d2.y = __builtin_amdgcn_perm(__float_as_uint(p[ns][3]),
                                   __float_as_uint(p[ns][2]), 0x07060302u);
      *(uint2*)((char*)myps + pwoff[ns]) = d2;
    }
    // Intra-wave LDS write->read: drain explicitly (consumer is a ds_read,
    // so the "memory" clobber fully orders it).
    asm volatile("s_waitcnt lgkmcnt(0)" ::: "memory");
    // ---- P B-frags: col=qrow(lo), k=key ks*32+hi*8 contiguous-8 ----
    short8 pf[2];
#pragma unroll
    for (int ks = 0; ks < 2; ++ks)
      pf[ks] = *(const short8*)((char*)myps + proff[ks]);
    // ---- O^T += V^T P^T (A=vf d-rows from LDS, B=pf; setprio m191) ----
    __builtin_amdgcn_s_setprio(1);
#pragma unroll
    for (int ns = 0; ns < 4; ++ns)
#pragma unroll
      for (int ks = 0; ks < 2; ++ks) {
        short8 vf = *(const short8*)(Vl + kvoff[ns][ks]);
        Ot[ns] = __builtin_amdgcn_mfma_f32_16x16x32_bf16(vf, pf[ks], Ot[ns], 0, 0, 0);
      }
    __builtin_amdgcn_s_setprio(0);
    __syncthreads();  // drains gld_lds (vmcnt) + orders buffer reuse
  }
  // ---- epilogue: normalize, write CTX [B,N,768] bf16, ushort4 stores ----
  const int bb = bh / NH, h = bh % NH;
  const float inv = frcp(lrun);
  const int n = q0 + lo;
#pragma unroll
  for (int ns = 0; ns < 4; ++ns) {
    ushort4 o;
    o.x = f2bf(Ot[ns][0] * inv); o.y = f2bf(Ot[ns][1] * inv);
    o.z = f2bf(Ot[ns][2] * inv); o.w = f2bf(Ot[ns][3] * inv);
    *(ushort4*)&CTX[(size_t)(bb * SEQ + n) * DIN + h * DH + ns * 16 + hi * 4] = o;
  }
}

// ---------------------------------------------------------------------------
extern "C" void kernel_launch(void* const* d_in, const int* in_sizes, int n_in,
                              void* d_out, int out_size, void* d_ws, size_t ws_size,
                              hipStream_t stream) {
  const float* x     = (const float*)d_in[0];
  const float* w_qkv = (const float*)d_in[1];
  const float* w_out = (const float*)d_in[2];
  const float* b_out = (const float*)d_in[3];
  float* out = (float*)d_out;

  ushort* ws = (ushort*)d_ws;
  const size_t nX   = (size_t)BATCH * SEQ * DIN;     // 3,145,728
  const size_t nWq  = (size_t)DIN * QKVN;            // 1,769,472
  const size_t nWo  = (size_t)DIN * DIN;             //   589,824
  const size_t nQKV = (size_t)BATCH * NH * SEQ * DH; // 3,145,728

  ushort* xb   = ws;
  ushort* wqT  = xb + nX;
  ushort* woT  = wqT + nWq;
  ushort* Qb   = woT + nWo;
  ushort* Kb   = Qb + nQKV;
  ushort* Vt   = Kb + nQKV;
  ushort* CTX  = Vt + nQKV;   // total ~36.2 MB

  cvt_all<<<dim3(5376), 256, 0, stream>>>(x, xb, w_qkv, wqT, w_out, woT);
  gemm_qkv<<<dim3(BATCH * SEQ / 128, QKVN / 128), 256, 0, stream>>>(
      xb, wqT, Qb, Kb, Vt);
  attn<<<dim3(SEQ / 64 * NBH), 256, 0, stream>>>(Qb, Kb, Vt, CTX);
  gemm_out<<<dim3(BATCH * SEQ / 64, DIN / 64), 256, 0, stream>>>(
      CTX, woT, b_out, out);
}